// Round 1
// baseline (409.509 us; speedup 1.0000x reference)
//
#include <hip/hip_runtime.h>

// Heston Euler-Maruyama: 100000 paths x 512 steps, fp32.
// One wave (64 threads) per 64 paths; time processed in 16-step chunks.
// Per-lane float4 loads of z (each lane streams its own path, full-line use);
// outputs staged in LDS and stored coalesced (dword-contiguous across lanes).

#define N_PATHS 100000
#define N_STEPS 512
#define TROW    1539      // (N_STEPS+1)*3 floats per output path row
#define ZROW    1024      // N_STEPS*2 floats per z path row

#define CSTEP   16        // steps per chunk
#define NCHUNK  (N_STEPS / CSTEP)   // 32
#define PB      64        // paths per block (one wave)

__global__ __launch_bounds__(PB) void heston_kernel(const float* __restrict__ z,
                                                    float* __restrict__ out) {
    __shared__ float ol[PB][3 * CSTEP + 1];   // 64 x 49 floats, +1 pad kills bank conflicts

    const int tid = threadIdx.x;
    const int p0  = blockIdx.x * PB;
    const int p   = p0 + tid;
    const bool act = (p < N_PATHS);

    const float DTc   = 0.004f;
    const float THETA = 0.04f;
    const float SIGMA = 0.2f;
    const float RHO   = -0.7f;
    const float S0c   = 100.0f;
    const float V0c   = 0.04f;
    const float sqdt  = 0.06324555320f;   // sqrt(0.004)
    const float csq   = 0.71414284285f;   // sqrt(1 - rho^2)
    const float TAU0  = 2.048f;           // N_STEPS * DT

    float s   = S0c;
    float v   = V0c;
    float acc = V0c;                      // running cumsum of variances (incl. t=0)

    // ---- t = 0 outputs (uniform across paths), coalesced-ish once per block ----
    {
        const float e0  = __expf(-TAU0);
        const float vs0 = fmaf(acc, DTc, fmaf(THETA, TAU0, (V0c - THETA) * (1.0f - e0)));
        for (int k = tid; k < PB * 3; k += PB) {
            int pl = k / 3;
            int si = k - pl * 3;
            if (p0 + pl < N_PATHS) {
                float val = (si == 0) ? S0c : (si == 1) ? V0c : vs0;
                out[(p0 + pl) * TROW + si] = val;
            }
        }
    }

    const float4* zp4 = act ? reinterpret_cast<const float4*>(z + (size_t)p * ZROW)
                            : reinterpret_cast<const float4*>(z);

    for (int c = 0; c < NCHUNK; ++c) {
        // ---- load this chunk's z for my path: 16 steps x 2 = 32 floats = 8 float4 ----
        float4 r[8];
        #pragma unroll
        for (int j = 0; j < 8; ++j) {
            r[j] = act ? zp4[c * 8 + j] : make_float4(0.f, 0.f, 0.f, 0.f);
        }

        // ---- 16 Euler steps, results into LDS tile ----
        #pragma unroll
        for (int dt = 0; dt < CSTEP; ++dt) {
            const float4 q = r[dt >> 1];
            const float z0 = (dt & 1) ? q.z : q.x;
            const float z1 = (dt & 1) ? q.w : q.y;

            const float vp  = fmaxf(v, 0.0f);
            const float sv  = sqrtf(vp);
            const float dW1 = sqdt * z0;
            const float dW2 = fmaf(RHO, dW1, (csq * sqdt) * z1);
            s = fmaf(s * sv, dW1, s);
            v = fmaxf(fmaf(SIGMA * sv, dW2, fmaf(THETA - vp, DTc, v)), 0.0f);
            acc += v;

            const int   t   = c * CSTEP + dt + 1;
            const float tau = fmaf((float)t, -DTc, TAU0);
            const float e   = __expf(-tau);
            const float vs  = fmaf(acc, DTc, fmaf(THETA, tau, (v - THETA) * (1.0f - e)));

            ol[tid][3 * dt + 0] = s;
            ol[tid][3 * dt + 1] = v;
            ol[tid][3 * dt + 2] = vs;
        }

        __syncthreads();

        // ---- cooperative coalesced store: 64 paths x 48 dwords ----
        const int base = 48 * c + 3;   // float offset within a path's output row
        {
            int pl = tid / 48;         // 64 = 48 + 16 -> per k: pl += 1, si += 16 (w/ carry)
            int si = tid - pl * 48;
            #pragma unroll
            for (int k = 0; k < 48; ++k) {
                if (p0 + pl < N_PATHS) {
                    out[(p0 + pl) * TROW + base + si] = ol[pl][si];
                }
                pl += 1;
                si += 16;
                int carry = (si >= 48) ? 1 : 0;
                si -= carry * 48;
                pl += carry;
            }
        }

        __syncthreads();   // protect ol before next chunk's compute overwrites it
    }
}

extern "C" void kernel_launch(void* const* d_in, const int* in_sizes, int n_in,
                              void* d_out, int out_size, void* d_ws, size_t ws_size,
                              hipStream_t stream) {
    const float* z = (const float*)d_in[0];
    float* out = (float*)d_out;
    const int nblocks = (N_PATHS + PB - 1) / PB;   // 1563
    heston_kernel<<<nblocks, PB, 0, stream>>>(z, out);
}

// Round 2
// 385.563 us; speedup vs baseline: 1.0621x; 1.0621x over previous
//
#include <hip/hip_runtime.h>

// Heston Euler-Maruyama: 100000 paths x 512 steps, fp32.
// One wave per 64 paths. Per chunk (16 steps):
//   - prefetch next chunk's z COALESCED (8 float4 instrs, 8 contiguous lines each)
//   - compute 16 steps reading z from a conflict-free LDS tile (stride 34)
//   - stage (s,v,varswap) in LDS, store coalesced with hoisted offsets
// Incremental exp for the analytic varswap leg (1 mul/step instead of expf).

#define N_PATHS 100000
#define N_STEPS 512
#define TROW    1539              // (N_STEPS+1)*3 floats per output path
#define CSTEP   16
#define NCHUNK  (N_STEPS / CSTEP) // 32
#define PB      64                // paths per block = one wave
#define ZSTR    34                // zl row stride (floats): b64 reads 4-way = min-phase, conflict-free
#define OSTR    49                // ol row stride (floats): odd stride -> 2-way on b32 = free

__global__ __launch_bounds__(PB, 2)
void heston_kernel(const float* __restrict__ z, float* __restrict__ out) {
    __shared__ float zl[PB * ZSTR];   // 8.7 KB
    __shared__ float ol[PB * OSTR];   // 12.5 KB

    const int tid = threadIdx.x;
    const int p0  = blockIdx.x * PB;
    const int lim = N_PATHS - p0;             // active paths in this block
    const bool ragged = (lim < PB);

    const float DTc   = 0.004f;
    const float THETA = 0.04f;
    const float SIGMA = 0.2f;
    const float RHO   = -0.7f;
    const float S0c   = 100.0f;
    const float V0c   = 0.04f;
    const float sqdt  = 0.06324555320f;       // sqrt(DT)
    const float csdt  = 0.71414284285f * 0.06324555320f;  // sqrt(1-rho^2)*sqrt(DT)
    const float TAU0  = 2.048f;               // N_STEPS*DT
    const float EDT   = expf(DTc);            // constant-folded
    const float E0    = expf(-TAU0);

    // ---- per-j coalesced-load voffsets (path-clamped: no OOB reads) ----
    int voff[8];
    #pragma unroll
    for (int j = 0; j < 8; ++j) {
        int pj = p0 + (tid >> 3) + 8 * j;
        if (pj > N_PATHS - 1) pj = N_PATHS - 1;
        voff[j] = pj * 4096 + (tid & 7) * 16;     // byte offset into z
    }
    const char* zb = (const char*)z;

    // ---- prologue: fill zl with chunk 0 ----
    {
        float4 f[8];
        #pragma unroll
        for (int j = 0; j < 8; ++j) f[j] = *(const float4*)(zb + voff[j]);
        #pragma unroll
        for (int j = 0; j < 8; ++j) {
            float2* d = (float2*)&zl[((tid >> 3) + 8 * j) * ZSTR + (tid & 7) * 4];
            d[0] = make_float2(f[j].x, f[j].y);
            d[1] = make_float2(f[j].z, f[j].w);
        }
    }

    // ---- t = 0 header ----
    {
        const float vs0 = fmaf(V0c, DTc, fmaf(THETA, TAU0, (V0c - THETA) * (1.0f - E0)));
        #pragma unroll
        for (int k = 0; k < 3; ++k) {
            int idx = k * PB + tid;           // 0..191
            int pl = idx / 3, si = idx - pl * 3;
            if (pl < lim)
                out[(p0 + pl) * TROW + si] = (si == 0) ? S0c : (si == 1) ? V0c : vs0;
        }
    }

    // ---- hoisted store offsets: pattern has period 3 in k (64 = 48+16) ----
    int gof[3], lof[3];
    {
        int pl = (tid >= 48) ? 1 : 0;
        int si = tid - pl * 48;
        #pragma unroll
        for (int j = 0; j < 3; ++j) {
            gof[j] = pl * TROW + si;
            lof[j] = pl * OSTR + si;
            pl += 1; si += 16;
            if (si >= 48) { si -= 48; pl += 1; }
        }
    }

    float s   = S0c;
    float v   = V0c;
    float acc = V0c;
    float tau = TAU0;
    float e   = E0;

    __syncthreads();

    for (int c = 0; c < NCHUNK; ++c) {
        // ---- issue coalesced prefetch of next chunk (overlaps compute) ----
        const int cn = ((c < NCHUNK - 1) ? (c + 1) : (NCHUNK - 1)) * 128;
        float4 f[8];
        #pragma unroll
        for (int j = 0; j < 8; ++j) f[j] = *(const float4*)(zb + voff[j] + cn);

        // ---- 16 Euler steps from zl ----
        #pragma unroll
        for (int dt = 0; dt < CSTEP; ++dt) {
            const float2 zz = *(const float2*)&zl[tid * ZSTR + 2 * dt];
            const float vp  = fmaxf(v, 0.0f);
            const float sv  = __builtin_amdgcn_sqrtf(vp);
            const float dW1 = sqdt * zz.x;
            const float dW2 = fmaf(RHO, dW1, csdt * zz.y);
            s = fmaf(s * sv, dW1, s);
            v = fmaxf(fmaf(SIGMA * sv, dW2, fmaf(THETA - vp, DTc, v)), 0.0f);
            acc += v;
            tau -= DTc;
            e *= EDT;
            const float vs = fmaf(acc, DTc, fmaf(THETA, tau, (v - THETA) * (1.0f - e)));
            ol[tid * OSTR + 3 * dt    ] = s;
            ol[tid * OSTR + 3 * dt + 1] = v;
            ol[tid * OSTR + 3 * dt + 2] = vs;
        }

        __syncthreads();   // ol visible cross-lane (also drains prefetch vmcnt)

        // ---- coalesced store: 64 paths x 48 dwords ----
        if (!ragged) {
            float* oc = out + (size_t)p0 * TROW + 3 + 48 * c;
            #pragma unroll
            for (int g = 0; g < 16; ++g) {
                #pragma unroll
                for (int j = 0; j < 3; ++j) {
                    oc[gof[j] + g * (4 * TROW)] = ol[lof[j] + g * (4 * OSTR)];
                }
            }
        } else {
            for (int k = 0; k < 48; ++k) {
                int idx = k * PB + tid;
                int pl2 = idx / 48, si2 = idx - pl2 * 48;
                if (pl2 < lim)
                    out[(size_t)(p0 + pl2) * TROW + 3 + 48 * c + si2] = ol[pl2 * OSTR + si2];
            }
        }

        // ---- write prefetched regs -> zl for next chunk ----
        #pragma unroll
        for (int j = 0; j < 8; ++j) {
            float2* d = (float2*)&zl[((tid >> 3) + 8 * j) * ZSTR + (tid & 7) * 4];
            d[0] = make_float2(f[j].x, f[j].y);
            d[1] = make_float2(f[j].z, f[j].w);
        }
        __syncthreads();
    }
}

extern "C" void kernel_launch(void* const* d_in, const int* in_sizes, int n_in,
                              void* d_out, int out_size, void* d_ws, size_t ws_size,
                              hipStream_t stream) {
    const float* z = (const float*)d_in[0];
    float* out = (float*)d_out;
    const int nblocks = (N_PATHS + PB - 1) / PB;   // 1563
    heston_kernel<<<nblocks, PB, 0, stream>>>(z, out);
}